// Round 8
// baseline (549.928 us; speedup 1.0000x reference)
//
#include <hip/hip_runtime.h>

// HellingerDistance: out[n][m] = 0.5*(rowsum_a[n] + rowsum_b[m]) - sqrt(a[n])·sqrt(b[m])
// N = M = 8192, D = 1024, f32 in/out.
// Round 8: 8-phase schedule with ONE-PHASE-AHEAD register pipeline:
// phase p = [ds_read regs for p+1 into alternate set][stage 1 half-tile]
//           [lgkmcnt(own) guard][16 MFMA k-outer][barrier].
// B-frags ping-pong per tile parity (read at p4/p8). vmcnt(2) gates p4/p8 reads.

#define NM 8192
#define DD 1024

typedef __attribute__((ext_vector_type(8))) short bf16x8;
typedef __attribute__((ext_vector_type(4))) float f32x4;

#define AS1 __attribute__((address_space(1)))
#define AS3 __attribute__((address_space(3)))

#define SCHED0 __builtin_amdgcn_sched_barrier(0)
#define WAIT_LGKM(n) do { SCHED0; asm volatile("s_waitcnt lgkmcnt(" #n ")" ::: "memory"); SCHED0; } while (0)
#define WAIT_VM(n)   do { SCHED0; asm volatile("s_waitcnt vmcnt(" #n ")" ::: "memory"); SCHED0; } while (0)
#define BAR __builtin_amdgcn_s_barrier()

// f32 -> bf16 round-to-nearest-even (inputs positive, no NaN/Inf)
static __device__ __forceinline__ unsigned short f2bf(float f) {
  unsigned int u = __float_as_uint(f);
  u += 0x7FFFu + ((u >> 16) & 1u);
  return (unsigned short)(u >> 16);
}

// ---------------- kernel 1: sqrt -> bf16, exact f32 rowsums ----------------
__global__ __launch_bounds__(256)
void hell_prep(const float* __restrict__ A, const float* __restrict__ B,
               unsigned short* __restrict__ SA, unsigned short* __restrict__ SB,
               float* __restrict__ RA, float* __restrict__ RB) {
  __shared__ float wsum[4];
  const int row = blockIdx.x & (NM - 1);
  const bool isB = blockIdx.x >= NM;
  const float* src = (isB ? B : A) + (size_t)row * DD;
  unsigned short* dst = (isB ? SB : SA) + (size_t)row * DD;
  const int t = threadIdx.x;
  const float4 v = ((const float4*)src)[t];
  ushort4 p;
  p.x = f2bf(sqrtf(v.x)); p.y = f2bf(sqrtf(v.y));
  p.z = f2bf(sqrtf(v.z)); p.w = f2bf(sqrtf(v.w));
  ((ushort4*)dst)[t] = p;
  float s = (v.x + v.y) + (v.z + v.w);
#pragma unroll
  for (int m = 1; m < 64; m <<= 1) s += __shfl_xor(s, m, 64);
  if ((t & 63) == 0) wsum[t >> 6] = s;
  __syncthreads();
  if (t == 0) (isB ? RB : RA)[row] = wsum[0] + wsum[1] + wsum[2] + wsum[3];
}

// ---------------- kernel 2: 256^2 8-phase, reads one phase ahead -----------
// LDS buf d at d*65536: A rows 0..255 (128B/row) at +0, B at +32768.
// Chunk c (16B) of row r stored at c ^ (r&7) (both-sides swizzle, rule 21).
__global__ __launch_bounds__(512, 2)
void hell_gemm7(const unsigned short* __restrict__ SA,
                const unsigned short* __restrict__ SB,
                const float* __restrict__ RA, const float* __restrict__ RB,
                float* __restrict__ C) {
  __shared__ __attribute__((aligned(16))) char lds[131072];

  const int t = threadIdx.x;
  const int lane = t & 63;
  const int wave = t >> 6;
  const int wm = wave >> 2;   // 0..1 -> rows wm*128
  const int wn = wave & 3;    // 0..3 -> cols wn*64

  // bijective XCD swizzle: nwg = 1024, 8 XCDs, chunk = 128
  const int wg = blockIdx.x;
  const int s = (wg & 7) * 128 + (wg >> 3);
  const int brow = (s >> 5) * 256;
  const int bcol = (s & 31) * 256;

  const int sw = ((t >> 3) & 7) ^ (t & 7);  // pre-swizzled source chunk

  const int hi = lane >> 4;
  const int lo = lane & 15;
  const int x7 = lo & 7;

  f32x4 acc[8][4];
#pragma unroll
  for (int m = 0; m < 8; ++m)
#pragma unroll
    for (int n = 0; n < 4; ++n) acc[m][n] = (f32x4){0.f, 0.f, 0.f, 0.f};

  bf16x8 afA[2][2], afB[2][2];     // A-quadrant ping-pong (per-phase)
  bf16x8 bfrE[4][2], bfrO[4][2];   // B-frags ping-pong (per-tile parity)

#define STAGE_HALF(MAT, BROW0, KT, LDSOFF)                                      \
  do {                                                                          \
    const unsigned short* g_ =                                                  \
        (MAT) + (size_t)((BROW0) + (t >> 3)) * DD + (size_t)(KT) * 64 + sw * 8; \
    __builtin_amdgcn_global_load_lds((const AS1 unsigned int*)g_,               \
        (AS3 unsigned int*)(lds + (LDSOFF) + t * 16), 16, 0, 0);                \
    __builtin_amdgcn_global_load_lds((const AS1 unsigned int*)(g_ + 64 * DD),   \
        (AS3 unsigned int*)(lds + (LDSOFF) + 8192 + t * 16), 16, 0, 0);         \
  } while (0)

#define SA_HALF(KT, BUF, H) STAGE_HALF(SA, brow + (H)*128, KT, (BUF)*65536 + (H)*16384)
#define SB_HALF(KT, BUF, H) STAGE_HALF(SB, bcol + (H)*128, KT, (BUF)*65536 + 32768 + (H)*16384)

#define LDA(SET, BASE, q)                                                       \
  do {                                                                          \
    _Pragma("unroll")                                                           \
    for (int m_ = 0; m_ < 2; ++m_) {                                            \
      const char* ra_ = (BASE) + (wm * 128 + ((q)*2 + m_) * 16 + lo) * 128;     \
      _Pragma("unroll")                                                         \
      for (int k_ = 0; k_ < 2; ++k_)                                            \
        SET[m_][k_] = *(const bf16x8*)(ra_ + (((k_ * 4 + hi) ^ x7) << 4));      \
    }                                                                           \
  } while (0)

#define LDB(SET, BASE)                                                          \
  do {                                                                          \
    _Pragma("unroll")                                                           \
    for (int n_ = 0; n_ < 4; ++n_) {                                            \
      const char* rb_ = (BASE) + 32768 + (wn * 64 + n_ * 16 + lo) * 128;        \
      _Pragma("unroll")                                                         \
      for (int k_ = 0; k_ < 2; ++k_)                                            \
        SET[n_][k_] = *(const bf16x8*)(rb_ + (((k_ * 4 + hi) ^ x7) << 4));      \
    }                                                                           \
  } while (0)

// k-outer: 8 independent MFMAs between dependent accumulator reuses
#define MFMA_Q(q, ASET, BSET)                                                   \
  do {                                                                          \
    __builtin_amdgcn_s_setprio(1);                                              \
    _Pragma("unroll")                                                           \
    for (int k_ = 0; k_ < 2; ++k_)                                              \
      _Pragma("unroll")                                                         \
      for (int m_ = 0; m_ < 2; ++m_)                                            \
        _Pragma("unroll")                                                       \
        for (int n_ = 0; n_ < 4; ++n_)                                          \
          acc[(q)*2 + m_][n_] = __builtin_amdgcn_mfma_f32_16x16x32_bf16(        \
              ASET[m_][k_], BSET[n_][k_], acc[(q)*2 + m_][n_], 0, 0, 0);        \
    __builtin_amdgcn_s_setprio(0);                                              \
  } while (0)

  const char* E = lds;
  const char* O = lds + 65536;

  // prologue: stage E0 (tile0 full) + O0.B (tile1 B); read E0.q0 + E0.B
  SA_HALF(0, 0, 0); SA_HALF(0, 0, 1);
  SB_HALF(0, 0, 0); SB_HALF(0, 0, 1);
  SB_HALF(1, 1, 0); SB_HALF(1, 1, 1);
  WAIT_VM(4);                    // E0's 8 landed; O0.B's 4 in flight
  BAR;
  LDA(afA, E, 0);
  LDB(bfrE, E);

#pragma unroll 1
  for (int it = 0; it < 8; ++it) {
    const int last = (it == 7);
    // p1: rd E.q1; stage odd.A0 (tile 2it+1); MFMA E.q0
    LDA(afB, E, 1); SA_HALF(2 * it + 1, 1, 0);
    WAIT_LGKM(4); MFMA_Q(0, afA, bfrE); BAR;
    // p2: rd E.q2; stage odd.A1; MFMA E.q1
    LDA(afA, E, 2); SA_HALF(2 * it + 1, 1, 1);
    WAIT_LGKM(4); MFMA_Q(1, afB, bfrE); BAR;
    // p3: rd E.q3; stage even.B0 (tile 2it+2); MFMA E.q2
    LDA(afB, E, 3);
    if (!last) SB_HALF(2 * it + 2, 0, 0);
    WAIT_LGKM(4); MFMA_Q(2, afA, bfrE); BAR;
    // p4: vmcnt gate; rd O.q0 + O.B; stage even.B1; MFMA E.q3
    if (!last) WAIT_VM(2); else WAIT_VM(0);   // odd tile (A+B) landed
    LDA(afA, O, 0); LDB(bfrO, O);
    if (!last) SB_HALF(2 * it + 2, 0, 1);
    WAIT_LGKM(12); MFMA_Q(3, afB, bfrE); BAR;
    // p5: rd O.q1; stage even.A0; MFMA O.q0
    LDA(afB, O, 1);
    if (!last) SA_HALF(2 * it + 2, 0, 0);
    WAIT_LGKM(4); MFMA_Q(0, afA, bfrO); BAR;
    // p6: rd O.q2; stage even.A1; MFMA O.q1
    LDA(afA, O, 2);
    if (!last) SA_HALF(2 * it + 2, 0, 1);
    WAIT_LGKM(4); MFMA_Q(1, afB, bfrO); BAR;
    // p7: rd O.q3; stage odd.B0 (tile 2it+3); MFMA O.q2
    LDA(afB, O, 3);
    if (!last) SB_HALF(2 * it + 3, 1, 0);
    WAIT_LGKM(4); MFMA_Q(2, afA, bfrO); BAR;
    // p8: vmcnt gate; rd next-E.q0 + next-E.B; stage odd.B1; MFMA O.q3
    if (!last) {
      WAIT_VM(2);                             // next even tile landed
      LDA(afA, E, 0); LDB(bfrE, E);
      SB_HALF(2 * it + 3, 1, 1);
      WAIT_LGKM(12); MFMA_Q(3, afB, bfrO); BAR;
    } else {
      WAIT_LGKM(0); MFMA_Q(3, afB, bfrO);
    }
  }

#undef MFMA_Q
#undef LDB
#undef LDA
#undef SB_HALF
#undef SA_HALF
#undef STAGE_HALF

  // epilogue: C/D layout col=lane&15, row=(lane>>4)*4+j
  float hrb[4];
#pragma unroll
  for (int n = 0; n < 4; ++n)
    hrb[n] = 0.5f * RB[bcol + wn * 64 + n * 16 + lo];
#pragma unroll
  for (int m = 0; m < 8; ++m) {
    const int rbase = wm * 128 + m * 16 + hi * 4;
#pragma unroll
    for (int j = 0; j < 4; ++j) {
      const int row = rbase + j;
      const float ha = 0.5f * RA[brow + row];
      float* orow = C + (size_t)(brow + row) * NM + bcol;
#pragma unroll
      for (int n = 0; n < 4; ++n)
        orow[wn * 64 + n * 16 + lo] = ha + hrb[n] - acc[m][n][j];
    }
  }
}

// ---------------- fallback: fused kernel (if ws too small) -----------------
static __device__ __forceinline__ int swz(int row, int colbytes) {
  return (row * 128 + colbytes) ^ ((row & 7) << 4);
}

__global__ __launch_bounds__(256, 2)
void hellinger_fused(const float* __restrict__ A, const float* __restrict__ B,
                     float* __restrict__ C) {
  __shared__ unsigned short As[128 * 64];
  __shared__ unsigned short Bs[128 * 64];
  __shared__ float sA[128];
  __shared__ float sB[128];

  const int t = threadIdx.x;
  const int lane = t & 63;
  const int wave = t >> 6;
  const int wrow = (wave >> 1) * 64;
  const int wcol = (wave & 1) * 64;
  const int brow = blockIdx.y * 128;
  const int bcol = blockIdx.x * 128;
  const int sr = t >> 4;
  const int sc = (t & 15) * 4;

  const float* ap = A + (size_t)(brow + sr) * DD + sc;
  const float* bp = B + (size_t)(bcol + sr) * DD + sc;

  float racc[8], cacc[8];
#pragma unroll
  for (int i = 0; i < 8; ++i) { racc[i] = 0.f; cacc[i] = 0.f; }

  f32x4 acc[4][4];
#pragma unroll
  for (int m = 0; m < 4; ++m)
#pragma unroll
    for (int n = 0; n < 4; ++n) acc[m][n] = (f32x4){0.f, 0.f, 0.f, 0.f};

  for (int kt = 0; kt < DD / 64; ++kt) {
#pragma unroll
    for (int i = 0; i < 8; ++i) {
      const float4 v = *(const float4*)(ap + (size_t)(i * 16) * DD + kt * 64);
      racc[i] += (v.x + v.y) + (v.z + v.w);
      ushort4 p;
      p.x = f2bf(sqrtf(v.x)); p.y = f2bf(sqrtf(v.y));
      p.z = f2bf(sqrtf(v.z)); p.w = f2bf(sqrtf(v.w));
      *(ushort4*)((char*)As + swz(i * 16 + sr, sc * 2)) = p;
    }
#pragma unroll
    for (int i = 0; i < 8; ++i) {
      const float4 v = *(const float4*)(bp + (size_t)(i * 16) * DD + kt * 64);
      cacc[i] += (v.x + v.y) + (v.z + v.w);
      ushort4 p;
      p.x = f2bf(sqrtf(v.x)); p.y = f2bf(sqrtf(v.y));
      p.z = f2bf(sqrtf(v.z)); p.w = f2bf(sqrtf(v.w));
      *(ushort4*)((char*)Bs + swz(i * 16 + sr, sc * 2)) = p;
    }
    __syncthreads();
#pragma unroll
    for (int kk = 0; kk < 2; ++kk) {
      const int koffb = kk * 64 + (lane >> 4) * 16;
      bf16x8 af[4], bfr[4];
#pragma unroll
      for (int m = 0; m < 4; ++m)
        af[m] = *(const bf16x8*)((const char*)As + swz(wrow + m * 16 + (lane & 15), koffb));
#pragma unroll
      for (int n = 0; n < 4; ++n)
        bfr[n] = *(const bf16x8*)((const char*)Bs + swz(wcol + n * 16 + (lane & 15), koffb));
#pragma unroll
      for (int m = 0; m < 4; ++m)
#pragma unroll
        for (int n = 0; n < 4; ++n)
          acc[m][n] = __builtin_amdgcn_mfma_f32_16x16x32_bf16(af[m], bfr[n], acc[m][n], 0, 0, 0);
    }
    __syncthreads();
  }

#pragma unroll
  for (int i = 0; i < 8; ++i) {
#pragma unroll
    for (int mask = 1; mask < 16; mask <<= 1) {
      racc[i] += __shfl_xor(racc[i], mask, 64);
      cacc[i] += __shfl_xor(cacc[i], mask, 64);
    }
  }
  if ((t & 15) == 0) {
#pragma unroll
    for (int i = 0; i < 8; ++i) { sA[i * 16 + sr] = racc[i]; sB[i * 16 + sr] = cacc[i]; }
  }
  __syncthreads();

#pragma unroll
  for (int m = 0; m < 4; ++m) {
    const int rbase = wrow + m * 16 + (lane >> 4) * 4;
#pragma unroll
    for (int j = 0; j < 4; ++j) {
      const int row = rbase + j;
      const float ha = 0.5f * sA[row];
      float* orow = C + (size_t)(brow + row) * NM + bcol;
#pragma unroll
      for (int n = 0; n < 4; ++n) {
        const int col = wcol + n * 16 + (lane & 15);
        orow[col] = ha + 0.5f * sB[col] - acc[m][n][j];
      }
    }
  }
}

extern "C" void kernel_launch(void* const* d_in, const int* in_sizes, int n_in,
                              void* d_out, int out_size, void* d_ws, size_t ws_size,
                              hipStream_t stream) {
  const float* a = (const float*)d_in[0];
  const float* b = (const float*)d_in[1];
  float* out = (float*)d_out;

  const size_t mat_bytes = (size_t)NM * DD * sizeof(unsigned short); // 16 MB
  const size_t need = 2 * mat_bytes + 2 * (size_t)NM * sizeof(float);

  if (ws_size >= need) {
    unsigned short* SA = (unsigned short*)d_ws;
    unsigned short* SB = (unsigned short*)((char*)d_ws + mat_bytes);
    float* RA = (float*)((char*)d_ws + 2 * mat_bytes);
    float* RB = RA + NM;
    hipLaunchKernelGGL(hell_prep, dim3(2 * NM), dim3(256), 0, stream,
                       a, b, SA, SB, RA, RB);
    hipLaunchKernelGGL(hell_gemm7, dim3(32 * 32), dim3(512), 0, stream,
                       SA, SB, RA, RB, out);
  } else {
    dim3 grid(NM / 128, NM / 128);
    hipLaunchKernelGGL(hellinger_fused, grid, dim3(256), 0, stream, a, b, out);
  }
}

// Round 9
// 549.073 us; speedup vs baseline: 1.0016x; 1.0016x over previous
//
#include <hip/hip_runtime.h>

// HellingerDistance: out[n][m] = 0.5*(rowsum_a[n] + rowsum_b[m]) - sqrt(a[n])·sqrt(b[m])
// N = M = 8192, D = 1024, f32 in/out.
// Round 9: identical pipeline to round 8, but __launch_bounds__(512, 1).
// Round 8's (512,2) acted as a 128-VGPR cap (2nd arg ~ min blocks/CU -> 4
// waves/SIMD) and the ~220-live-reg pipeline spilled to scratch (1.1GB extra
// writes). A 512-thread block is inherently 2 waves/SIMD -> cap 256; (512,1)
// lets the allocator use it.

#define NM 8192
#define DD 1024

typedef __attribute__((ext_vector_type(8))) short bf16x8;
typedef __attribute__((ext_vector_type(4))) float f32x4;

#define AS1 __attribute__((address_space(1)))
#define AS3 __attribute__((address_space(3)))

#define SCHED0 __builtin_amdgcn_sched_barrier(0)
#define WAIT_LGKM(n) do { SCHED0; asm volatile("s_waitcnt lgkmcnt(" #n ")" ::: "memory"); SCHED0; } while (0)
#define WAIT_VM(n)   do { SCHED0; asm volatile("s_waitcnt vmcnt(" #n ")" ::: "memory"); SCHED0; } while (0)
#define BAR __builtin_amdgcn_s_barrier()

// f32 -> bf16 round-to-nearest-even (inputs positive, no NaN/Inf)
static __device__ __forceinline__ unsigned short f2bf(float f) {
  unsigned int u = __float_as_uint(f);
  u += 0x7FFFu + ((u >> 16) & 1u);
  return (unsigned short)(u >> 16);
}

// ---------------- kernel 1: sqrt -> bf16, exact f32 rowsums ----------------
__global__ __launch_bounds__(256)
void hell_prep(const float* __restrict__ A, const float* __restrict__ B,
               unsigned short* __restrict__ SA, unsigned short* __restrict__ SB,
               float* __restrict__ RA, float* __restrict__ RB) {
  __shared__ float wsum[4];
  const int row = blockIdx.x & (NM - 1);
  const bool isB = blockIdx.x >= NM;
  const float* src = (isB ? B : A) + (size_t)row * DD;
  unsigned short* dst = (isB ? SB : SA) + (size_t)row * DD;
  const int t = threadIdx.x;
  const float4 v = ((const float4*)src)[t];
  ushort4 p;
  p.x = f2bf(sqrtf(v.x)); p.y = f2bf(sqrtf(v.y));
  p.z = f2bf(sqrtf(v.z)); p.w = f2bf(sqrtf(v.w));
  ((ushort4*)dst)[t] = p;
  float s = (v.x + v.y) + (v.z + v.w);
#pragma unroll
  for (int m = 1; m < 64; m <<= 1) s += __shfl_xor(s, m, 64);
  if ((t & 63) == 0) wsum[t >> 6] = s;
  __syncthreads();
  if (t == 0) (isB ? RB : RA)[row] = wsum[0] + wsum[1] + wsum[2] + wsum[3];
}

// ---------------- kernel 2: 256^2 8-phase, reads one phase ahead -----------
// LDS buf d at d*65536: A rows 0..255 (128B/row) at +0, B at +32768.
// Chunk c (16B) of row r stored at c ^ (r&7) (both-sides swizzle, rule 21).
__global__ __launch_bounds__(512, 1)
void hell_gemm8(const unsigned short* __restrict__ SA,
                const unsigned short* __restrict__ SB,
                const float* __restrict__ RA, const float* __restrict__ RB,
                float* __restrict__ C) {
  __shared__ __attribute__((aligned(16))) char lds[131072];

  const int t = threadIdx.x;
  const int lane = t & 63;
  const int wave = t >> 6;
  const int wm = wave >> 2;   // 0..1 -> rows wm*128
  const int wn = wave & 3;    // 0..3 -> cols wn*64

  // bijective XCD swizzle: nwg = 1024, 8 XCDs, chunk = 128
  const int wg = blockIdx.x;
  const int s = (wg & 7) * 128 + (wg >> 3);
  const int brow = (s >> 5) * 256;
  const int bcol = (s & 31) * 256;

  const int sw = ((t >> 3) & 7) ^ (t & 7);  // pre-swizzled source chunk

  const int hi = lane >> 4;
  const int lo = lane & 15;
  const int x7 = lo & 7;

  f32x4 acc[8][4];
#pragma unroll
  for (int m = 0; m < 8; ++m)
#pragma unroll
    for (int n = 0; n < 4; ++n) acc[m][n] = (f32x4){0.f, 0.f, 0.f, 0.f};

  bf16x8 afA[2][2], afB[2][2];     // A-quadrant ping-pong (per-phase)
  bf16x8 bfrE[4][2], bfrO[4][2];   // B-frags ping-pong (per-tile parity)

#define STAGE_HALF(MAT, BROW0, KT, LDSOFF)                                      \
  do {                                                                          \
    const unsigned short* g_ =                                                  \
        (MAT) + (size_t)((BROW0) + (t >> 3)) * DD + (size_t)(KT) * 64 + sw * 8; \
    __builtin_amdgcn_global_load_lds((const AS1 unsigned int*)g_,               \
        (AS3 unsigned int*)(lds + (LDSOFF) + t * 16), 16, 0, 0);                \
    __builtin_amdgcn_global_load_lds((const AS1 unsigned int*)(g_ + 64 * DD),   \
        (AS3 unsigned int*)(lds + (LDSOFF) + 8192 + t * 16), 16, 0, 0);         \
  } while (0)

#define SA_HALF(KT, BUF, H) STAGE_HALF(SA, brow + (H)*128, KT, (BUF)*65536 + (H)*16384)
#define SB_HALF(KT, BUF, H) STAGE_HALF(SB, bcol + (H)*128, KT, (BUF)*65536 + 32768 + (H)*16384)

#define LDA(SET, BASE, q)                                                       \
  do {                                                                          \
    _Pragma("unroll")                                                           \
    for (int m_ = 0; m_ < 2; ++m_) {                                            \
      const char* ra_ = (BASE) + (wm * 128 + ((q)*2 + m_) * 16 + lo) * 128;     \
      _Pragma("unroll")                                                         \
      for (int k_ = 0; k_ < 2; ++k_)                                            \
        SET[m_][k_] = *(const bf16x8*)(ra_ + (((k_ * 4 + hi) ^ x7) << 4));      \
    }                                                                           \
  } while (0)

#define LDB(SET, BASE)                                                          \
  do {                                                                          \
    _Pragma("unroll")                                                           \
    for (int n_ = 0; n_ < 4; ++n_) {                                            \
      const char* rb_ = (BASE) + 32768 + (wn * 64 + n_ * 16 + lo) * 128;        \
      _Pragma("unroll")                                                         \
      for (int k_ = 0; k_ < 2; ++k_)                                            \
        SET[n_][k_] = *(const bf16x8*)(rb_ + (((k_ * 4 + hi) ^ x7) << 4));      \
    }                                                                           \
  } while (0)

// k-outer: 8 independent MFMAs between dependent accumulator reuses
#define MFMA_Q(q, ASET, BSET)                                                   \
  do {                                                                          \
    __builtin_amdgcn_s_setprio(1);                                              \
    _Pragma("unroll")                                                           \
    for (int k_ = 0; k_ < 2; ++k_)                                              \
      _Pragma("unroll")                                                         \
      for (int m_ = 0; m_ < 2; ++m_)                                            \
        _Pragma("unroll")                                                       \
        for (int n_ = 0; n_ < 4; ++n_)                                          \
          acc[(q)*2 + m_][n_] = __builtin_amdgcn_mfma_f32_16x16x32_bf16(        \
              ASET[m_][k_], BSET[n_][k_], acc[(q)*2 + m_][n_], 0, 0, 0);        \
    __builtin_amdgcn_s_setprio(0);                                              \
  } while (0)

  const char* E = lds;
  const char* O = lds + 65536;

  // prologue: stage E0 (tile0 full) + O0.B (tile1 B); read E0.q0 + E0.B
  SA_HALF(0, 0, 0); SA_HALF(0, 0, 1);
  SB_HALF(0, 0, 0); SB_HALF(0, 0, 1);
  SB_HALF(1, 1, 0); SB_HALF(1, 1, 1);
  WAIT_VM(4);                    // E0's 8 landed; O0.B's 4 in flight
  BAR;
  LDA(afA, E, 0);
  LDB(bfrE, E);

#pragma unroll 1
  for (int it = 0; it < 8; ++it) {
    const int last = (it == 7);
    // p1: rd E.q1; stage odd.A0 (tile 2it+1); MFMA E.q0
    LDA(afB, E, 1); SA_HALF(2 * it + 1, 1, 0);
    WAIT_LGKM(4); MFMA_Q(0, afA, bfrE); BAR;
    // p2: rd E.q2; stage odd.A1; MFMA E.q1
    LDA(afA, E, 2); SA_HALF(2 * it + 1, 1, 1);
    WAIT_LGKM(4); MFMA_Q(1, afB, bfrE); BAR;
    // p3: rd E.q3; stage even.B0 (tile 2it+2); MFMA E.q2
    LDA(afB, E, 3);
    if (!last) SB_HALF(2 * it + 2, 0, 0);
    WAIT_LGKM(4); MFMA_Q(2, afA, bfrE); BAR;
    // p4: vmcnt gate; rd O.q0 + O.B; stage even.B1; MFMA E.q3
    if (!last) WAIT_VM(2); else WAIT_VM(0);   // odd tile (A+B) landed
    LDA(afA, O, 0); LDB(bfrO, O);
    if (!last) SB_HALF(2 * it + 2, 0, 1);
    WAIT_LGKM(12); MFMA_Q(3, afB, bfrE); BAR;
    // p5: rd O.q1; stage even.A0; MFMA O.q0
    LDA(afB, O, 1);
    if (!last) SA_HALF(2 * it + 2, 0, 0);
    WAIT_LGKM(4); MFMA_Q(0, afA, bfrO); BAR;
    // p6: rd O.q2; stage even.A1; MFMA O.q1
    LDA(afA, O, 2);
    if (!last) SA_HALF(2 * it + 2, 0, 1);
    WAIT_LGKM(4); MFMA_Q(1, afB, bfrO); BAR;
    // p7: rd O.q3; stage odd.B0 (tile 2it+3); MFMA O.q2
    LDA(afB, O, 3);
    if (!last) SB_HALF(2 * it + 3, 1, 0);
    WAIT_LGKM(4); MFMA_Q(2, afA, bfrO); BAR;
    // p8: vmcnt gate; rd next-E.q0 + next-E.B; stage odd.B1; MFMA O.q3
    if (!last) {
      WAIT_VM(2);                             // next even tile landed
      LDA(afA, E, 0); LDB(bfrE, E);
      SB_HALF(2 * it + 3, 1, 1);
      WAIT_LGKM(12); MFMA_Q(3, afB, bfrO); BAR;
    } else {
      WAIT_LGKM(0); MFMA_Q(3, afB, bfrO);
    }
  }

#undef MFMA_Q
#undef LDB
#undef LDA
#undef SB_HALF
#undef SA_HALF
#undef STAGE_HALF

  // epilogue: C/D layout col=lane&15, row=(lane>>4)*4+j
  float hrb[4];
#pragma unroll
  for (int n = 0; n < 4; ++n)
    hrb[n] = 0.5f * RB[bcol + wn * 64 + n * 16 + lo];
#pragma unroll
  for (int m = 0; m < 8; ++m) {
    const int rbase = wm * 128 + m * 16 + hi * 4;
#pragma unroll
    for (int j = 0; j < 4; ++j) {
      const int row = rbase + j;
      const float ha = 0.5f * RA[brow + row];
      float* orow = C + (size_t)(brow + row) * NM + bcol;
#pragma unroll
      for (int n = 0; n < 4; ++n)
        orow[wn * 64 + n * 16 + lo] = ha + hrb[n] - acc[m][n][j];
    }
  }
}

// ---------------- fallback: fused kernel (if ws too small) -----------------
static __device__ __forceinline__ int swz(int row, int colbytes) {
  return (row * 128 + colbytes) ^ ((row & 7) << 4);
}

__global__ __launch_bounds__(256, 2)
void hellinger_fused(const float* __restrict__ A, const float* __restrict__ B,
                     float* __restrict__ C) {
  __shared__ unsigned short As[128 * 64];
  __shared__ unsigned short Bs[128 * 64];
  __shared__ float sA[128];
  __shared__ float sB[128];

  const int t = threadIdx.x;
  const int lane = t & 63;
  const int wave = t >> 6;
  const int wrow = (wave >> 1) * 64;
  const int wcol = (wave & 1) * 64;
  const int brow = blockIdx.y * 128;
  const int bcol = blockIdx.x * 128;
  const int sr = t >> 4;
  const int sc = (t & 15) * 4;

  const float* ap = A + (size_t)(brow + sr) * DD + sc;
  const float* bp = B + (size_t)(bcol + sr) * DD + sc;

  float racc[8], cacc[8];
#pragma unroll
  for (int i = 0; i < 8; ++i) { racc[i] = 0.f; cacc[i] = 0.f; }

  f32x4 acc[4][4];
#pragma unroll
  for (int m = 0; m < 4; ++m)
#pragma unroll
    for (int n = 0; n < 4; ++n) acc[m][n] = (f32x4){0.f, 0.f, 0.f, 0.f};

  for (int kt = 0; kt < DD / 64; ++kt) {
#pragma unroll
    for (int i = 0; i < 8; ++i) {
      const float4 v = *(const float4*)(ap + (size_t)(i * 16) * DD + kt * 64);
      racc[i] += (v.x + v.y) + (v.z + v.w);
      ushort4 p;
      p.x = f2bf(sqrtf(v.x)); p.y = f2bf(sqrtf(v.y));
      p.z = f2bf(sqrtf(v.z)); p.w = f2bf(sqrtf(v.w));
      *(ushort4*)((char*)As + swz(i * 16 + sr, sc * 2)) = p;
    }
#pragma unroll
    for (int i = 0; i < 8; ++i) {
      const float4 v = *(const float4*)(bp + (size_t)(i * 16) * DD + kt * 64);
      cacc[i] += (v.x + v.y) + (v.z + v.w);
      ushort4 p;
      p.x = f2bf(sqrtf(v.x)); p.y = f2bf(sqrtf(v.y));
      p.z = f2bf(sqrtf(v.z)); p.w = f2bf(sqrtf(v.w));
      *(ushort4*)((char*)Bs + swz(i * 16 + sr, sc * 2)) = p;
    }
    __syncthreads();
#pragma unroll
    for (int kk = 0; kk < 2; ++kk) {
      const int koffb = kk * 64 + (lane >> 4) * 16;
      bf16x8 af[4], bfr[4];
#pragma unroll
      for (int m = 0; m < 4; ++m)
        af[m] = *(const bf16x8*)((const char*)As + swz(wrow + m * 16 + (lane & 15), koffb));
#pragma unroll
      for (int n = 0; n < 4; ++n)
        bfr[n] = *(const bf16x8*)((const char*)Bs + swz(wcol + n * 16 + (lane & 15), koffb));
#pragma unroll
      for (int m = 0; m < 4; ++m)
#pragma unroll
        for (int n = 0; n < 4; ++n)
          acc[m][n] = __builtin_amdgcn_mfma_f32_16x16x32_bf16(af[m], bfr[n], acc[m][n], 0, 0, 0);
    }
    __syncthreads();
  }

#pragma unroll
  for (int i = 0; i < 8; ++i) {
#pragma unroll
    for (int mask = 1; mask < 16; mask <<= 1) {
      racc[i] += __shfl_xor(racc[i], mask, 64);
      cacc[i] += __shfl_xor(cacc[i], mask, 64);
    }
  }
  if ((t & 15) == 0) {
#pragma unroll
    for (int i = 0; i < 8; ++i) { sA[i * 16 + sr] = racc[i]; sB[i * 16 + sr] = cacc[i]; }
  }
  __syncthreads();

#pragma unroll
  for (int m = 0; m < 4; ++m) {
    const int rbase = wrow + m * 16 + (lane >> 4) * 4;
#pragma unroll
    for (int j = 0; j < 4; ++j) {
      const int row = rbase + j;
      const float ha = 0.5f * sA[row];
      float* orow = C + (size_t)(brow + row) * NM + bcol;
#pragma unroll
      for (int n = 0; n < 4; ++n) {
        const int col = wcol + n * 16 + (lane & 15);
        orow[col] = ha + 0.5f * sB[col] - acc[m][n][j];
      }
    }
  }
}

extern "C" void kernel_launch(void* const* d_in, const int* in_sizes, int n_in,
                              void* d_out, int out_size, void* d_ws, size_t ws_size,
                              hipStream_t stream) {
  const float* a = (const float*)d_in[0];
  const float* b = (const float*)d_in[1];
  float* out = (float*)d_out;

  const size_t mat_bytes = (size_t)NM * DD * sizeof(unsigned short); // 16 MB
  const size_t need = 2 * mat_bytes + 2 * (size_t)NM * sizeof(float);

  if (ws_size >= need) {
    unsigned short* SA = (unsigned short*)d_ws;
    unsigned short* SB = (unsigned short*)((char*)d_ws + mat_bytes);
    float* RA = (float*)((char*)d_ws + 2 * mat_bytes);
    float* RB = RA + NM;
    hipLaunchKernelGGL(hell_prep, dim3(2 * NM), dim3(256), 0, stream,
                       a, b, SA, SB, RA, RB);
    hipLaunchKernelGGL(hell_gemm8, dim3(32 * 32), dim3(512), 0, stream,
                       SA, SB, RA, RB, out);
  } else {
    dim3 grid(NM / 128, NM / 128);
    hipLaunchKernelGGL(hellinger_fused, grid, dim3(256), 0, stream, a, b, out);
  }
}

// Round 10
// 181.413 us; speedup vs baseline: 3.0314x; 3.0266x over previous
//
#include <hip/hip_runtime.h>

// HellingerDistance: out[n][m] = 0.5*(rowsum_a[n] + rowsum_b[m]) - sqrt(a[n])·sqrt(b[m])
// N = M = 8192, D = 1024, f32 in/out.
// Round 10: r7 structure (current-phase reads, 8-phase, both-sides swizzle,
// VM(4) gates at p4/p8) + PERSISTENT blocks: 256 blocks, 4 output tiles each,
// staging ring continues across tiles (it==7 stages next tile's K0/K1), epilogue
// overlapped between tiles. Plus k-outer MFMA (independent accumulator chains).

#define NM 8192
#define DD 1024

typedef __attribute__((ext_vector_type(8))) short bf16x8;
typedef __attribute__((ext_vector_type(4))) float f32x4;

#define AS1 __attribute__((address_space(1)))
#define AS3 __attribute__((address_space(3)))

#define SCHED0 __builtin_amdgcn_sched_barrier(0)
#define WAIT_LGKM0  do { SCHED0; asm volatile("s_waitcnt lgkmcnt(0)" ::: "memory"); SCHED0; } while (0)
#define WAIT_VM(n)  do { SCHED0; asm volatile("s_waitcnt vmcnt(" #n ")" ::: "memory"); SCHED0; } while (0)
#define BAR __builtin_amdgcn_s_barrier()

// f32 -> bf16 round-to-nearest-even (inputs positive, no NaN/Inf)
static __device__ __forceinline__ unsigned short f2bf(float f) {
  unsigned int u = __float_as_uint(f);
  u += 0x7FFFu + ((u >> 16) & 1u);
  return (unsigned short)(u >> 16);
}

// ---------------- kernel 1: sqrt -> bf16, exact f32 rowsums ----------------
__global__ __launch_bounds__(256)
void hell_prep(const float* __restrict__ A, const float* __restrict__ B,
               unsigned short* __restrict__ SA, unsigned short* __restrict__ SB,
               float* __restrict__ RA, float* __restrict__ RB) {
  __shared__ float wsum[4];
  const int row = blockIdx.x & (NM - 1);
  const bool isB = blockIdx.x >= NM;
  const float* src = (isB ? B : A) + (size_t)row * DD;
  unsigned short* dst = (isB ? SB : SA) + (size_t)row * DD;
  const int t = threadIdx.x;
  const float4 v = ((const float4*)src)[t];
  ushort4 p;
  p.x = f2bf(sqrtf(v.x)); p.y = f2bf(sqrtf(v.y));
  p.z = f2bf(sqrtf(v.z)); p.w = f2bf(sqrtf(v.w));
  ((ushort4*)dst)[t] = p;
  float s = (v.x + v.y) + (v.z + v.w);
#pragma unroll
  for (int m = 1; m < 64; m <<= 1) s += __shfl_xor(s, m, 64);
  if ((t & 63) == 0) wsum[t >> 6] = s;
  __syncthreads();
  if (t == 0) (isB ? RB : RA)[row] = wsum[0] + wsum[1] + wsum[2] + wsum[3];
}

// ---------------- kernel 2: persistent 256^2 8-phase bf16 GEMM -------------
// LDS buf d at d*65536: A rows 0..255 (128B/row) at +0, B at +32768.
// Chunk c (16B) of row r stored at c ^ (r&7) (both-sides swizzle).
__global__ __launch_bounds__(512, 1)
void hell_gemm9(const unsigned short* __restrict__ SA,
                const unsigned short* __restrict__ SB,
                const float* __restrict__ RA, const float* __restrict__ RB,
                float* __restrict__ C) {
  __shared__ __attribute__((aligned(16))) char lds[131072];

  const int t = threadIdx.x;
  const int lane = t & 63;
  const int wave = t >> 6;
  const int wm = wave >> 2;   // 0..1 -> rows wm*128
  const int wn = wave & 3;    // 0..3 -> cols wn*64

  const int b = blockIdx.x;   // 256 blocks; tiles s = 128*(b&7) + (b>>3)*4 + j
  const int sbase = (b & 7) * 128 + (b >> 3) * 4;

  const int sw = ((t >> 3) & 7) ^ (t & 7);  // pre-swizzled source chunk

  const int hi = lane >> 4;
  const int lo = lane & 15;
  const int x7 = lo & 7;

  bf16x8 af[2][2];   // current-phase A quadrant
  bf16x8 bfr[4][2];  // per-K-tile B fragments

#define STAGE_HALF(MAT, BROW0, KT, LDSOFF)                                      \
  do {                                                                          \
    const unsigned short* g_ =                                                  \
        (MAT) + (size_t)((BROW0) + (t >> 3)) * DD + (size_t)(KT) * 64 + sw * 8; \
    __builtin_amdgcn_global_load_lds((const AS1 unsigned int*)g_,               \
        (AS3 unsigned int*)(lds + (LDSOFF) + t * 16), 16, 0, 0);                \
    __builtin_amdgcn_global_load_lds((const AS1 unsigned int*)(g_ + 64 * DD),   \
        (AS3 unsigned int*)(lds + (LDSOFF) + 8192 + t * 16), 16, 0, 0);         \
  } while (0)

#define SA_HALF(BR, KT, BUF, H) STAGE_HALF(SA, (BR) + (H)*128, KT, (BUF)*65536 + (H)*16384)
#define SB_HALF(BC, KT, BUF, H) STAGE_HALF(SB, (BC) + (H)*128, KT, (BUF)*65536 + 32768 + (H)*16384)

#define LDA(BASE, q)                                                            \
  do {                                                                          \
    _Pragma("unroll")                                                           \
    for (int m_ = 0; m_ < 2; ++m_) {                                            \
      const char* ra_ = (BASE) + (wm * 128 + ((q)*2 + m_) * 16 + lo) * 128;     \
      _Pragma("unroll")                                                         \
      for (int k_ = 0; k_ < 2; ++k_)                                            \
        af[m_][k_] = *(const bf16x8*)(ra_ + (((k_ * 4 + hi) ^ x7) << 4));       \
    }                                                                           \
  } while (0)

#define LDB(BASE)                                                               \
  do {                                                                          \
    _Pragma("unroll")                                                           \
    for (int n_ = 0; n_ < 4; ++n_) {                                            \
      const char* rb_ = (BASE) + 32768 + (wn * 64 + n_ * 16 + lo) * 128;        \
      _Pragma("unroll")                                                         \
      for (int k_ = 0; k_ < 2; ++k_)                                            \
        bfr[n_][k_] = *(const bf16x8*)(rb_ + (((k_ * 4 + hi) ^ x7) << 4));      \
    }                                                                           \
  } while (0)

// k-outer: 8 independent MFMAs between dependent accumulator reuses
#define MFMA_Q(q)                                                               \
  do {                                                                          \
    __builtin_amdgcn_s_setprio(1);                                              \
    _Pragma("unroll")                                                           \
    for (int k_ = 0; k_ < 2; ++k_)                                              \
      _Pragma("unroll")                                                         \
      for (int m_ = 0; m_ < 2; ++m_)                                            \
        _Pragma("unroll")                                                       \
        for (int n_ = 0; n_ < 4; ++n_)                                          \
          acc[(q)*2 + m_][n_] = __builtin_amdgcn_mfma_f32_16x16x32_bf16(        \
              af[m_][k_], bfr[n_][k_], acc[(q)*2 + m_][n_], 0, 0, 0);           \
    __builtin_amdgcn_s_setprio(0);                                              \
  } while (0)

  const char* E = lds;           // buf0: even K-tiles
  const char* O = lds + 65536;   // buf1: odd K-tiles

  // prologue for tile j=0: E0 (A0+B0) + O.B1
  {
    const int s0 = sbase;
    const int br0 = (s0 >> 5) * 256, bc0 = (s0 & 31) * 256;
    SA_HALF(br0, 0, 0, 0); SA_HALF(br0, 0, 0, 1);
    SB_HALF(bc0, 0, 0, 0); SB_HALF(bc0, 0, 0, 1);
    SB_HALF(bc0, 1, 1, 0); SB_HALF(bc0, 1, 1, 1);
    WAIT_VM(4);                 // E0's 8 landed; O.B1's 4 in flight
    BAR;
  }

#pragma unroll 1
  for (int j = 0; j < 4; ++j) {
    const int s1 = sbase + j;
    const int brow = (s1 >> 5) * 256, bcol = (s1 & 31) * 256;
    const int brow2 = ((s1 + 1) >> 5) * 256, bcol2 = ((s1 + 1) & 31) * 256;

    f32x4 acc[8][4];
#pragma unroll
    for (int m = 0; m < 8; ++m)
#pragma unroll
      for (int n = 0; n < 4; ++n) acc[m][n] = (f32x4){0.f, 0.f, 0.f, 0.f};

#pragma unroll 1
    for (int it = 0; it < 8; ++it) {
      const bool wrap = (it == 7);
      const bool lastall = (j == 3) && wrap;
      // staging targets: current tile until it==7, then next tile's K0/K1
      const int brN = wrap ? brow2 : brow;
      const int bcN = wrap ? bcol2 : bcol;
      const int kE = wrap ? 0 : 2 * it + 2;  // even-buf target K-tile
      const int kO = wrap ? 1 : 2 * it + 3;  // odd-buf B target K-tile

      // p1: E q0 + B-frags; stage odd.A(2it+1) h0
      LDB(E); LDA(E, 0);
      SA_HALF(brow, 2 * it + 1, 1, 0);
      BAR; WAIT_LGKM0; MFMA_Q(0); BAR;
      // p2: E q1; stage odd.A h1
      LDA(E, 1);
      SA_HALF(brow, 2 * it + 1, 1, 1);
      BAR; WAIT_LGKM0; MFMA_Q(1); BAR;
      // p3: E q2; stage even.B(kE) h0
      LDA(E, 2);
      if (!lastall) SB_HALF(bcN, kE, 0, 0);
      BAR; WAIT_LGKM0; MFMA_Q(2); BAR;
      // p4: E q3; stage even.B h1; counted vmcnt (odd tile landed)
      LDA(E, 3);
      if (!lastall) { SB_HALF(bcN, kE, 0, 1); WAIT_VM(4); }
      else          { WAIT_VM(0); }
      BAR; WAIT_LGKM0; MFMA_Q(3); BAR;
      // p5: O q0 + B-frags; stage even.A(kE) h0
      LDB(O); LDA(O, 0);
      if (!lastall) SA_HALF(brN, kE, 0, 0);
      BAR; WAIT_LGKM0; MFMA_Q(0); BAR;
      // p6: O q1; stage even.A h1
      LDA(O, 1);
      if (!lastall) SA_HALF(brN, kE, 0, 1);
      BAR; WAIT_LGKM0; MFMA_Q(1); BAR;
      // p7: O q2; stage odd.B(kO) h0
      LDA(O, 2);
      if (!lastall) SB_HALF(bcN, kO, 1, 0);
      BAR; WAIT_LGKM0; MFMA_Q(2); BAR;
      // p8: O q3; stage odd.B h1; counted vmcnt (even tile landed)
      LDA(O, 3);
      if (!lastall) { SB_HALF(bcN, kO, 1, 1); WAIT_VM(4); }
      BAR; WAIT_LGKM0; MFMA_Q(3); BAR;
    }

    // per-tile epilogue: C/D layout col=lane&15, row=(lane>>4)*4+jj
    {
      float hrb[4];
#pragma unroll
      for (int n = 0; n < 4; ++n)
        hrb[n] = 0.5f * RB[bcol + wn * 64 + n * 16 + lo];
#pragma unroll
      for (int m = 0; m < 8; ++m) {
        const int rbase = wm * 128 + m * 16 + hi * 4;
#pragma unroll
        for (int jj = 0; jj < 4; ++jj) {
          const int row = rbase + jj;
          const float ha = 0.5f * RA[brow + row];
          float* orow = C + (size_t)(brow + row) * NM + bcol;
#pragma unroll
          for (int n = 0; n < 4; ++n)
            orow[wn * 64 + n * 16 + lo] = ha + hrb[n] - acc[m][n][jj];
        }
      }
    }
    if (j < 3) WAIT_VM(0);  // drain stores (L2 ack) + already-landed loads
  }

#undef MFMA_Q
#undef LDB
#undef LDA
#undef SB_HALF
#undef SA_HALF
#undef STAGE_HALF
}

// ---------------- fallback: fused kernel (if ws too small) -----------------
static __device__ __forceinline__ int swz(int row, int colbytes) {
  return (row * 128 + colbytes) ^ ((row & 7) << 4);
}

__global__ __launch_bounds__(256, 2)
void hellinger_fused(const float* __restrict__ A, const float* __restrict__ B,
                     float* __restrict__ C) {
  __shared__ unsigned short As[128 * 64];
  __shared__ unsigned short Bs[128 * 64];
  __shared__ float sA[128];
  __shared__ float sB[128];

  const int t = threadIdx.x;
  const int lane = t & 63;
  const int wave = t >> 6;
  const int wrow = (wave >> 1) * 64;
  const int wcol = (wave & 1) * 64;
  const int brow = blockIdx.y * 128;
  const int bcol = blockIdx.x * 128;
  const int sr = t >> 4;
  const int sc = (t & 15) * 4;

  const float* ap = A + (size_t)(brow + sr) * DD + sc;
  const float* bp = B + (size_t)(bcol + sr) * DD + sc;

  float racc[8], cacc[8];
#pragma unroll
  for (int i = 0; i < 8; ++i) { racc[i] = 0.f; cacc[i] = 0.f; }

  f32x4 acc[4][4];
#pragma unroll
  for (int m = 0; m < 4; ++m)
#pragma unroll
    for (int n = 0; n < 4; ++n) acc[m][n] = (f32x4){0.f, 0.f, 0.f, 0.f};

  for (int kt = 0; kt < DD / 64; ++kt) {
#pragma unroll
    for (int i = 0; i < 8; ++i) {
      const float4 v = *(const float4*)(ap + (size_t)(i * 16) * DD + kt * 64);
      racc[i] += (v.x + v.y) + (v.z + v.w);
      ushort4 p;
      p.x = f2bf(sqrtf(v.x)); p.y = f2bf(sqrtf(v.y));
      p.z = f2bf(sqrtf(v.z)); p.w = f2bf(sqrtf(v.w));
      *(ushort4*)((char*)As + swz(i * 16 + sr, sc * 2)) = p;
    }
#pragma unroll
    for (int i = 0; i < 8; ++i) {
      const float4 v = *(const float4*)(bp + (size_t)(i * 16) * DD + kt * 64);
      cacc[i] += (v.x + v.y) + (v.z + v.w);
      ushort4 p;
      p.x = f2bf(sqrtf(v.x)); p.y = f2bf(sqrtf(v.y));
      p.z = f2bf(sqrtf(v.z)); p.w = f2bf(sqrtf(v.w));
      *(ushort4*)((char*)Bs + swz(i * 16 + sr, sc * 2)) = p;
    }
    __syncthreads();
#pragma unroll
    for (int kk = 0; kk < 2; ++kk) {
      const int koffb = kk * 64 + (lane >> 4) * 16;
      bf16x8 af[4], bfr[4];
#pragma unroll
      for (int m = 0; m < 4; ++m)
        af[m] = *(const bf16x8*)((const char*)As + swz(wrow + m * 16 + (lane & 15), koffb));
#pragma unroll
      for (int n = 0; n < 4; ++n)
        bfr[n] = *(const bf16x8*)((const char*)Bs + swz(wcol + n * 16 + (lane & 15), koffb));
#pragma unroll
      for (int m = 0; m < 4; ++m)
#pragma unroll
        for (int n = 0; n < 4; ++n)
          acc[m][n] = __builtin_amdgcn_mfma_f32_16x16x32_bf16(af[m], bfr[n], acc[m][n], 0, 0, 0);
    }
    __syncthreads();
  }

#pragma unroll
  for (int i = 0; i < 8; ++i) {
#pragma unroll
    for (int mask = 1; mask < 16; mask <<= 1) {
      racc[i] += __shfl_xor(racc[i], mask, 64);
      cacc[i] += __shfl_xor(cacc[i], mask, 64);
    }
  }
  if ((t & 15) == 0) {
#pragma unroll
    for (int i = 0; i < 8; ++i) { sA[i * 16 + sr] = racc[i]; sB[i * 16 + sr] = cacc[i]; }
  }
  __syncthreads();

#pragma unroll
  for (int m = 0; m < 4; ++m) {
    const int rbase = wrow + m * 16 + (lane >> 4) * 4;
#pragma unroll
    for (int j = 0; j < 4; ++j) {
      const int row = rbase + j;
      const float ha = 0.5f * sA[row];
      float* orow = C + (size_t)(brow + row) * NM + bcol;
#pragma unroll
      for (int n = 0; n < 4; ++n) {
        const int col = wcol + n * 16 + (lane & 15);
        orow[col] = ha + 0.5f * sB[col] - acc[m][n][j];
      }
    }
  }
}

extern "C" void kernel_launch(void* const* d_in, const int* in_sizes, int n_in,
                              void* d_out, int out_size, void* d_ws, size_t ws_size,
                              hipStream_t stream) {
  const float* a = (const float*)d_in[0];
  const float* b = (const float*)d_in[1];
  float* out = (float*)d_out;

  const size_t mat_bytes = (size_t)NM * DD * sizeof(unsigned short); // 16 MB
  const size_t need = 2 * mat_bytes + 2 * (size_t)NM * sizeof(float);

  if (ws_size >= need) {
    unsigned short* SA = (unsigned short*)d_ws;
    unsigned short* SB = (unsigned short*)((char*)d_ws + mat_bytes);
    float* RA = (float*)((char*)d_ws + 2 * mat_bytes);
    float* RB = RA + NM;
    hipLaunchKernelGGL(hell_prep, dim3(2 * NM), dim3(256), 0, stream,
                       a, b, SA, SB, RA, RB);
    hipLaunchKernelGGL(hell_gemm9, dim3(256), dim3(512), 0, stream,
                       SA, SB, RA, RB, out);
  } else {
    dim3 grid(NM / 128, NM / 128);
    hipLaunchKernelGGL(hellinger_fused, grid, dim3(256), 0, stream, a, b, out);
  }
}

// Round 11
// 169.008 us; speedup vs baseline: 3.2538x; 1.0734x over previous
//
#include <hip/hip_runtime.h>

// HellingerDistance: out[n][m] = 0.5*(rowsum_a[n] + rowsum_b[m]) - sqrt(a[n])·sqrt(b[m])
// N = M = 8192, D = 1024, f32 in/out.
// Round 11: balanced k-slice phases (4 per 2 K-tiles: 12 reads + 32 MFMA each)
// with partial counted-lgkm ladder (lgkm 6/4/2/0 between 8-MFMA bursts) so the
// DS pipe serves reads UNDER the MFMA bursts. Staging ring distance-2, gates
// VM(4) at P1/P3 only. Both-sides swizzle, XCD swizzle, grid 1024.

#define NM 8192
#define DD 1024

typedef __attribute__((ext_vector_type(8))) short bf16x8;
typedef __attribute__((ext_vector_type(4))) float f32x4;

#define AS1 __attribute__((address_space(1)))
#define AS3 __attribute__((address_space(3)))

#define SCHED0 __builtin_amdgcn_sched_barrier(0)
#define WAIT_LGKM(n) do { SCHED0; asm volatile("s_waitcnt lgkmcnt(" #n ")" ::: "memory"); SCHED0; } while (0)
#define WAIT_VM(n)   do { SCHED0; asm volatile("s_waitcnt vmcnt(" #n ")" ::: "memory"); SCHED0; } while (0)
#define BAR __builtin_amdgcn_s_barrier()

// f32 -> bf16 round-to-nearest-even (inputs positive, no NaN/Inf)
static __device__ __forceinline__ unsigned short f2bf(float f) {
  unsigned int u = __float_as_uint(f);
  u += 0x7FFFu + ((u >> 16) & 1u);
  return (unsigned short)(u >> 16);
}

// ---------------- kernel 1: sqrt -> bf16, exact f32 rowsums ----------------
__global__ __launch_bounds__(256)
void hell_prep(const float* __restrict__ A, const float* __restrict__ B,
               unsigned short* __restrict__ SA, unsigned short* __restrict__ SB,
               float* __restrict__ RA, float* __restrict__ RB) {
  __shared__ float wsum[4];
  const int row = blockIdx.x & (NM - 1);
  const bool isB = blockIdx.x >= NM;
  const float* src = (isB ? B : A) + (size_t)row * DD;
  unsigned short* dst = (isB ? SB : SA) + (size_t)row * DD;
  const int t = threadIdx.x;
  const float4 v = ((const float4*)src)[t];
  ushort4 p;
  p.x = f2bf(sqrtf(v.x)); p.y = f2bf(sqrtf(v.y));
  p.z = f2bf(sqrtf(v.z)); p.w = f2bf(sqrtf(v.w));
  ((ushort4*)dst)[t] = p;
  float s = (v.x + v.y) + (v.z + v.w);
#pragma unroll
  for (int m = 1; m < 64; m <<= 1) s += __shfl_xor(s, m, 64);
  if ((t & 63) == 0) wsum[t >> 6] = s;
  __syncthreads();
  if (t == 0) (isB ? RB : RA)[row] = wsum[0] + wsum[1] + wsum[2] + wsum[3];
}

// ---------------- kernel 2: 256^2 k-slice-phase bf16 GEMM ------------------
// LDS buf d at d*65536: A rows 0..255 (128B/row) at +0, B at +32768.
// Chunk c (16B) of row r stored at c ^ (r&7) (both-sides swizzle).
__global__ __launch_bounds__(512, 1)
void hell_gemm10(const unsigned short* __restrict__ SA,
                 const unsigned short* __restrict__ SB,
                 const float* __restrict__ RA, const float* __restrict__ RB,
                 float* __restrict__ C) {
  __shared__ __attribute__((aligned(16))) char lds[131072];

  const int t = threadIdx.x;
  const int lane = t & 63;
  const int wave = t >> 6;
  const int wm = wave >> 2;   // 0..1 -> rows wm*128
  const int wn = wave & 3;    // 0..3 -> cols wn*64

  // bijective XCD swizzle: nwg = 1024, 8 XCDs, chunk = 128
  const int wg = blockIdx.x;
  const int s = (wg & 7) * 128 + (wg >> 3);
  const int brow = (s >> 5) * 256;
  const int bcol = (s & 31) * 256;

  const int sw = ((t >> 3) & 7) ^ (t & 7);  // pre-swizzled source chunk

  const int hi = lane >> 4;
  const int lo = lane & 15;
  const int x7 = lo & 7;

  f32x4 acc[8][4];
#pragma unroll
  for (int m = 0; m < 8; ++m)
#pragma unroll
    for (int n = 0; n < 4; ++n) acc[m][n] = (f32x4){0.f, 0.f, 0.f, 0.f};

  bf16x8 af[8];    // per-phase A fragments (all 8 m, one k-half)
  bf16x8 bfr[4];   // per-phase B fragments (all 4 n, one k-half)

#define STAGE_HALF(MAT, BROW0, KT, LDSOFF)                                      \
  do {                                                                          \
    const unsigned short* g_ =                                                  \
        (MAT) + (size_t)((BROW0) + (t >> 3)) * DD + (size_t)(KT) * 64 + sw * 8; \
    __builtin_amdgcn_global_load_lds((const AS1 unsigned int*)g_,               \
        (AS3 unsigned int*)(lds + (LDSOFF) + t * 16), 16, 0, 0);                \
    __builtin_amdgcn_global_load_lds((const AS1 unsigned int*)(g_ + 64 * DD),   \
        (AS3 unsigned int*)(lds + (LDSOFF) + 8192 + t * 16), 16, 0, 0);         \
  } while (0)

#define SA_FULL(KT, BUF)                                                        \
  do {                                                                          \
    STAGE_HALF(SA, brow, KT, (BUF)*65536);                                      \
    STAGE_HALF(SA, brow + 128, KT, (BUF)*65536 + 16384);                        \
  } while (0)
#define SB_FULL(KT, BUF)                                                        \
  do {                                                                          \
    STAGE_HALF(SB, bcol, KT, (BUF)*65536 + 32768);                              \
    STAGE_HALF(SB, bcol + 128, KT, (BUF)*65536 + 32768 + 16384);                \
  } while (0)

// reads: B first (4), then A (8) — ladder counts depend on this order
#define LDB_K(BASE, kh)                                                         \
  do {                                                                          \
    _Pragma("unroll")                                                           \
    for (int n_ = 0; n_ < 4; ++n_)                                              \
      bfr[n_] = *(const bf16x8*)((BASE) + 32768 +                               \
          (wn * 64 + n_ * 16 + lo) * 128 + ((((kh)*4 + hi) ^ x7) << 4));        \
  } while (0)

#define LDA_ALL(BASE, kh)                                                       \
  do {                                                                          \
    _Pragma("unroll")                                                           \
    for (int m_ = 0; m_ < 8; ++m_)                                              \
      af[m_] = *(const bf16x8*)((BASE) +                                        \
          (wm * 128 + m_ * 16 + lo) * 128 + ((((kh)*4 + hi) ^ x7) << 4));       \
  } while (0)

// 8 independent MFMAs (m-pair x all n), no acc reuse within burst
#define BURST(p)                                                                \
  do {                                                                          \
    _Pragma("unroll")                                                           \
    for (int n_ = 0; n_ < 4; ++n_) {                                            \
      acc[2*(p)][n_]   = __builtin_amdgcn_mfma_f32_16x16x32_bf16(               \
          af[2*(p)],   bfr[n_], acc[2*(p)][n_],   0, 0, 0);                     \
      acc[2*(p)+1][n_] = __builtin_amdgcn_mfma_f32_16x16x32_bf16(               \
          af[2*(p)+1], bfr[n_], acc[2*(p)+1][n_], 0, 0, 0);                     \
    }                                                                           \
  } while (0)

// partial-drain ladder: first burst after 6 reads land; DS serves rest under MFMA
#define LADDER()                                                                \
  do {                                                                          \
    __builtin_amdgcn_s_setprio(1);                                              \
    WAIT_LGKM(6); BURST(0);                                                     \
    WAIT_LGKM(4); BURST(1);                                                     \
    WAIT_LGKM(2); BURST(2);                                                     \
    WAIT_LGKM(0); BURST(3);                                                     \
    __builtin_amdgcn_s_setprio(0);                                              \
  } while (0)

  const char* E = lds;           // buf0: even K-tiles
  const char* O = lds + 65536;   // buf1: odd K-tiles

  // prologue: stage tile0 (E) fully — plays the role of "P3/P4 of iter -1"
  SA_FULL(0, 0); SB_FULL(0, 0);

#pragma unroll 1
  for (int it = 0; it < 8; ++it) {
    const bool last = (it == 7);

    // P1: stage O.A(2it+1); gate E (8 oldest of 12); read E k0; ladder
    SA_FULL(2 * it + 1, 1);
    WAIT_VM(4);
    BAR;
    LDB_K(E, 0); SCHED0; LDA_ALL(E, 0);
    LADDER();
    BAR;

    // P2: stage O.B; read E k1 (E already gated)
    SB_FULL(2 * it + 1, 1);
    BAR;
    LDB_K(E, 1); SCHED0; LDA_ALL(E, 1);
    LADDER();
    BAR;

    // P3: stage E'.A(2it+2); gate O; read O k0
    if (!last) { SA_FULL(2 * it + 2, 0); WAIT_VM(4); }
    else       { WAIT_VM(0); }
    BAR;
    LDB_K(O, 0); SCHED0; LDA_ALL(O, 0);
    LADDER();
    BAR;

    // P4: stage E'.B; read O k1
    if (!last) SB_FULL(2 * it + 2, 0);
    BAR;
    LDB_K(O, 1); SCHED0; LDA_ALL(O, 1);
    LADDER();
    BAR;
  }

#undef LADDER
#undef BURST
#undef LDA_ALL
#undef LDB_K
#undef SB_FULL
#undef SA_FULL
#undef STAGE_HALF

  // epilogue: C/D layout col=lane&15, row=(lane>>4)*4+j
  float hrb[4];
#pragma unroll
  for (int n = 0; n < 4; ++n)
    hrb[n] = 0.5f * RB[bcol + wn * 64 + n * 16 + lo];
#pragma unroll
  for (int m = 0; m < 8; ++m) {
    const int rbase = wm * 128 + m * 16 + hi * 4;
#pragma unroll
    for (int j = 0; j < 4; ++j) {
      const int row = rbase + j;
      const float ha = 0.5f * RA[brow + row];
      float* orow = C + (size_t)(brow + row) * NM + bcol;
#pragma unroll
      for (int n = 0; n < 4; ++n)
        orow[wn * 64 + n * 16 + lo] = ha + hrb[n] - acc[m][n][j];
    }
  }
}

// ---------------- fallback: fused kernel (if ws too small) -----------------
static __device__ __forceinline__ int swz(int row, int colbytes) {
  return (row * 128 + colbytes) ^ ((row & 7) << 4);
}

__global__ __launch_bounds__(256, 2)
void hellinger_fused(const float* __restrict__ A, const float* __restrict__ B,
                     float* __restrict__ C) {
  __shared__ unsigned short As[128 * 64];
  __shared__ unsigned short Bs[128 * 64];
  __shared__ float sA[128];
  __shared__ float sB[128];

  const int t = threadIdx.x;
  const int lane = t & 63;
  const int wave = t >> 6;
  const int wrow = (wave >> 1) * 64;
  const int wcol = (wave & 1) * 64;
  const int brow = blockIdx.y * 128;
  const int bcol = blockIdx.x * 128;
  const int sr = t >> 4;
  const int sc = (t & 15) * 4;

  const float* ap = A + (size_t)(brow + sr) * DD + sc;
  const float* bp = B + (size_t)(bcol + sr) * DD + sc;

  float racc[8], cacc[8];
#pragma unroll
  for (int i = 0; i < 8; ++i) { racc[i] = 0.f; cacc[i] = 0.f; }

  f32x4 acc[4][4];
#pragma unroll
  for (int m = 0; m < 4; ++m)
#pragma unroll
    for (int n = 0; n < 4; ++n) acc[m][n] = (f32x4){0.f, 0.f, 0.f, 0.f};

  for (int kt = 0; kt < DD / 64; ++kt) {
#pragma unroll
    for (int i = 0; i < 8; ++i) {
      const float4 v = *(const float4*)(ap + (size_t)(i * 16) * DD + kt * 64);
      racc[i] += (v.x + v.y) + (v.z + v.w);
      ushort4 p;
      p.x = f2bf(sqrtf(v.x)); p.y = f2bf(sqrtf(v.y));
      p.z = f2bf(sqrtf(v.z)); p.w = f2bf(sqrtf(v.w));
      *(ushort4*)((char*)As + swz(i * 16 + sr, sc * 2)) = p;
    }
#pragma unroll
    for (int i = 0; i < 8; ++i) {
      const float4 v = *(const float4*)(bp + (size_t)(i * 16) * DD + kt * 64);
      cacc[i] += (v.x + v.y) + (v.z + v.w);
      ushort4 p;
      p.x = f2bf(sqrtf(v.x)); p.y = f2bf(sqrtf(v.y));
      p.z = f2bf(sqrtf(v.z)); p.w = f2bf(sqrtf(v.w));
      *(ushort4*)((char*)Bs + swz(i * 16 + sr, sc * 2)) = p;
    }
    __syncthreads();
#pragma unroll
    for (int kk = 0; kk < 2; ++kk) {
      const int koffb = kk * 64 + (lane >> 4) * 16;
      bf16x8 af[4], bfr[4];
#pragma unroll
      for (int m = 0; m < 4; ++m)
        af[m] = *(const bf16x8*)((const char*)As + swz(wrow + m * 16 + (lane & 15), koffb));
#pragma unroll
      for (int n = 0; n < 4; ++n)
        bfr[n] = *(const bf16x8*)((const char*)Bs + swz(wcol + n * 16 + (lane & 15), koffb));
#pragma unroll
      for (int m = 0; m < 4; ++m)
#pragma unroll
        for (int n = 0; n < 4; ++n)
          acc[m][n] = __builtin_amdgcn_mfma_f32_16x16x32_bf16(af[m], bfr[n], acc[m][n], 0, 0, 0);
    }
    __syncthreads();
  }

#pragma unroll
  for (int i = 0; i < 8; ++i) {
#pragma unroll
    for (int mask = 1; mask < 16; mask <<= 1) {
      racc[i] += __shfl_xor(racc[i], mask, 64);
      cacc[i] += __shfl_xor(cacc[i], mask, 64);
    }
  }
  if ((t & 15) == 0) {
#pragma unroll
    for (int i = 0; i < 8; ++i) { sA[i * 16 + sr] = racc[i]; sB[i * 16 + sr] = cacc[i]; }
  }
  __syncthreads();

#pragma unroll
  for (int m = 0; m < 4; ++m) {
    const int rbase = wrow + m * 16 + (lane >> 4) * 4;
#pragma unroll
    for (int j = 0; j < 4; ++j) {
      const int row = rbase + j;
      const float ha = 0.5f * sA[row];
      float* orow = C + (size_t)(brow + row) * NM + bcol;
#pragma unroll
      for (int n = 0; n < 4; ++n) {
        const int col = wcol + n * 16 + (lane & 15);
        orow[col] = ha + 0.5f * sB[col] - acc[m][n][j];
      }
    }
  }
}

extern "C" void kernel_launch(void* const* d_in, const int* in_sizes, int n_in,
                              void* d_out, int out_size, void* d_ws, size_t ws_size,
                              hipStream_t stream) {
  const float* a = (const float*)d_in[0];
  const float* b = (const float*)d_in[1];
  float* out = (float*)d_out;

  const size_t mat_bytes = (size_t)NM * DD * sizeof(unsigned short); // 16 MB
  const size_t need = 2 * mat_bytes + 2 * (size_t)NM * sizeof(float);

  if (ws_size >= need) {
    unsigned short* SA = (unsigned short*)d_ws;
    unsigned short* SB = (unsigned short*)((char*)d_ws + mat_bytes);
    float* RA = (float*)((char*)d_ws + 2 * mat_bytes);
    float* RB = RA + NM;
    hipLaunchKernelGGL(hell_prep, dim3(2 * NM), dim3(256), 0, stream,
                       a, b, SA, SB, RA, RB);
    hipLaunchKernelGGL(hell_gemm10, dim3(32 * 32), dim3(512), 0, stream,
                       SA, SB, RA, RB, out);
  } else {
    dim3 grid(NM / 128, NM / 128);
    hipLaunchKernelGGL(hellinger_fused, grid, dim3(256), 0, stream, a, b, out);
  }
}